// Round 2
// baseline (677.285 us; speedup 1.0000x reference)
//
#include <hip/hip_runtime.h>
#include <hip/hip_bf16.h>
#include <hip/hip_fp16.h>
#include <math.h>

// Problem constants (fixed by the reference)
#define NN 1024      // proposals
#define DAPP 1024    // appearance dim
#define DK 64        // key dim
#define DG 64        // geo dim
#define NR 16        // relations

typedef __bf16 bf16x8 __attribute__((ext_vector_type(8)));
typedef _Float16 f16x8 __attribute__((ext_vector_type(8)));
typedef float f32x4 __attribute__((ext_vector_type(4)));

// ---------------- ws layout (bytes) ----------------
// fab  : bf16 [1024][1024]        @ OFF_FAB   (2 MB)
// Wb   : bf16 [3][16][64][1024]   @ OFF_WB    (6 MB)   (K,Q,V stacked; row j = proj*1024 + r*64 + d)
// Kb   : bf16 [16][1024][64]      @ OFF_KB    (2 MB)
// Qb   : bf16 [16][1024][64]      @ OFF_QB    (2 MB)
// V    : f32  [16][1024][64]      @ OFF_V     (4 MB)
// S    : f16  [16][1024][1024]    @ OFF_S     (32 MB)  scores -> w_mn (in-place fp16 RMW)
// stats: f32x2 [16*1024]          @ OFF_ST    (128 KB)
static constexpr size_t OFF_FAB = 0;
static constexpr size_t OFF_WB  = OFF_FAB + (size_t)NN * DAPP * 2;
static constexpr size_t OFF_KB  = OFF_WB + (size_t)3 * NR * DK * DAPP * 2;
static constexpr size_t OFF_QB  = OFF_KB + (size_t)NR * NN * DK * 2;
static constexpr size_t OFF_V   = OFF_QB + (size_t)NR * NN * DK * 2;
static constexpr size_t OFF_S   = OFF_V + (size_t)NR * NN * DK * 4;
static constexpr size_t OFF_ST  = OFF_S + (size_t)NR * NN * NN * 2;

// ---------------- K0: cast f_a and W{K,Q,V} to bf16 ----------------
__global__ __launch_bounds__(256) void cast_kernel(
    const float* __restrict__ fa, const float* __restrict__ wk,
    const float* __restrict__ wq, const float* __restrict__ wv,
    __bf16* __restrict__ fab, __bf16* __restrict__ wb) {
  int i = blockIdx.x * 256 + threadIdx.x;  // 0 .. 4M-1
  const int M1 = NN * DAPP;                // 1M
  if (i < M1) {
    fab[i] = (__bf16)fa[i];
  } else {
    int j = i - M1;                        // 0 .. 3M-1
    int p = j >> 20;
    int o = j & (M1 - 1);
    const float* src = (p == 0) ? wk : ((p == 1) ? wq : wv);
    wb[j] = (__bf16)src[o];
  }
}

// ---------------- K1: KQV projection, bf16 MFMA, fused bias ----------------
// C[n, j] = sum_f fab[n,f] * Wb[j,f],  j in [0,3072)
__global__ __launch_bounds__(256) void kqv_kernel(
    const __bf16* __restrict__ fab, const __bf16* __restrict__ wb,
    const float* __restrict__ kbias, const float* __restrict__ qbias,
    const float* __restrict__ vbias,
    __bf16* __restrict__ Kb, __bf16* __restrict__ Qb, float* __restrict__ V) {
  int wave = blockIdx.x * 4 + (threadIdx.x >> 6);  // 0..3071
  int l = threadIdx.x & 63;
  int nt = wave / 96;        // 32 n-tiles
  int jt = wave % 96;        // 96 j-tiles
  int n0 = nt * 32, j0 = jt * 32;
  int ra = l & 15;
  int ko = (l >> 4) * 8;

  f32x4 acc[2][2] = {};
  for (int k0 = 0; k0 < DAPP; k0 += 32) {
    bf16x8 a0 = *(const bf16x8*)(fab + (size_t)(n0 + ra) * DAPP + k0 + ko);
    bf16x8 a1 = *(const bf16x8*)(fab + (size_t)(n0 + 16 + ra) * DAPP + k0 + ko);
    bf16x8 b0 = *(const bf16x8*)(wb + (size_t)(j0 + ra) * DAPP + k0 + ko);
    bf16x8 b1 = *(const bf16x8*)(wb + (size_t)(j0 + 16 + ra) * DAPP + k0 + ko);
    acc[0][0] = __builtin_amdgcn_mfma_f32_16x16x32_bf16(a0, b0, acc[0][0], 0, 0, 0);
    acc[0][1] = __builtin_amdgcn_mfma_f32_16x16x32_bf16(a0, b1, acc[0][1], 0, 0, 0);
    acc[1][0] = __builtin_amdgcn_mfma_f32_16x16x32_bf16(a1, b0, acc[1][0], 0, 0, 0);
    acc[1][1] = __builtin_amdgcn_mfma_f32_16x16x32_bf16(a1, b1, acc[1][1], 0, 0, 0);
  }

  // C/D layout: col = lane&15, row = (lane>>4)*4 + reg
  #pragma unroll
  for (int i = 0; i < 2; i++) {
    #pragma unroll
    for (int jj = 0; jj < 2; jj++) {
      #pragma unroll
      for (int q = 0; q < 4; q++) {
        int n = n0 + i * 16 + (l >> 4) * 4 + q;
        int col = j0 + jj * 16 + (l & 15);
        int proj = col >> 10;
        int rd = col & 1023;          // r*64 + d
        int r = rd >> 6, d = rd & 63;
        float v = acc[i][jj][q];
        size_t oidx = ((size_t)r * NN + n) * DK + d;
        if (proj == 0)      Kb[oidx] = (__bf16)(v + kbias[rd]);
        else if (proj == 1) Qb[oidx] = (__bf16)(v + qbias[rd]);
        else                V[oidx] = v + vbias[rd];
      }
    }
  }
}

// ---------------- K2: scores S[r,n,m] = (K_rn . Q_rm) / 8, bf16 MFMA, fp16 out ----------------
__global__ __launch_bounds__(256) void scores_kernel(
    const __bf16* __restrict__ Kb, const __bf16* __restrict__ Qb,
    _Float16* __restrict__ S) {
  int wave = blockIdx.x * 4 + (threadIdx.x >> 6);  // 0..16383
  int r = wave >> 10;
  int idx = wave & 1023;
  int n0 = (idx >> 5) * 32;
  int m0 = (idx & 31) * 32;
  int l = threadIdx.x & 63;
  int ra = l & 15;
  int ko = (l >> 4) * 8;
  const __bf16* Kr = Kb + (size_t)r * NN * DK;
  const __bf16* Qr = Qb + (size_t)r * NN * DK;

  f32x4 acc[2][2] = {};
  #pragma unroll
  for (int k0 = 0; k0 < DK; k0 += 32) {
    bf16x8 a0 = *(const bf16x8*)(Kr + (n0 + ra) * DK + k0 + ko);
    bf16x8 a1 = *(const bf16x8*)(Kr + (n0 + 16 + ra) * DK + k0 + ko);
    bf16x8 b0 = *(const bf16x8*)(Qr + (m0 + ra) * DK + k0 + ko);
    bf16x8 b1 = *(const bf16x8*)(Qr + (m0 + 16 + ra) * DK + k0 + ko);
    acc[0][0] = __builtin_amdgcn_mfma_f32_16x16x32_bf16(a0, b0, acc[0][0], 0, 0, 0);
    acc[0][1] = __builtin_amdgcn_mfma_f32_16x16x32_bf16(a0, b1, acc[0][1], 0, 0, 0);
    acc[1][0] = __builtin_amdgcn_mfma_f32_16x16x32_bf16(a1, b0, acc[1][0], 0, 0, 0);
    acc[1][1] = __builtin_amdgcn_mfma_f32_16x16x32_bf16(a1, b1, acc[1][1], 0, 0, 0);
  }

  #pragma unroll
  for (int i = 0; i < 2; i++) {
    #pragma unroll
    for (int jj = 0; jj < 2; jj++) {
      #pragma unroll
      for (int q = 0; q < 4; q++) {
        int n = n0 + i * 16 + (l >> 4) * 4 + q;
        int m = m0 + jj * 16 + (l & 15);
        S[((size_t)r << 20) + ((size_t)n << 10) + m] = (_Float16)(acc[i][jj][q] * 0.125f);
      }
    }
  }
}

// ---------------- K3: fused gate + stats ----------------
// block = n (1024 blocks); thread t covers m = c*256+t, c=0..3.
// Gate dot in fp32 (precision: log-clip sensitivity). In-place S += logG (fp16).
// Online per-(r,n) max/sumexp, merged wave->block, written to stats.
__global__ __launch_bounds__(256) void gate_stats_kernel(
    const float* __restrict__ pe, const float* __restrict__ WGw,
    const float* __restrict__ WGb, _Float16* __restrict__ S,
    float2* __restrict__ stats) {
  __shared__ float4 wgt[16][16];  // [g4][r]
  __shared__ float wgb[16];
  __shared__ float2 red[16][4];
  int t = threadIdx.x;
  {
    int g4 = t >> 4, r = t & 15;
    wgt[g4][r] = ((const float4*)WGw)[r * 16 + g4];
    if (t < 16) wgb[t] = WGb[t];
  }
  __syncthreads();

  int n = blockIdx.x;
  float mx[16], lsum[16];
  #pragma unroll
  for (int r = 0; r < 16; r++) { mx[r] = -1e30f; lsum[r] = 0.f; }

  for (int c = 0; c < 4; c++) {
    int m = c * 256 + t;
    const float4* pe4 = (const float4*)(pe + (((size_t)n << 10) + m) * DG);
    float acc[16];
    #pragma unroll
    for (int r = 0; r < 16; r++) acc[r] = wgb[r];
    #pragma unroll
    for (int g4 = 0; g4 < 16; g4++) {
      float4 p = pe4[g4];
      #pragma unroll
      for (int r = 0; r < 16; r++) {
        float4 w = wgt[g4][r];
        acc[r] += p.x * w.x + p.y * w.y + p.z * w.z + p.w * w.w;
      }
    }
    size_t base = ((size_t)n << 10) + m;
    #pragma unroll
    for (int r = 0; r < 16; r++) {
      size_t idx = ((size_t)r << 20) + base;
      float v = (float)S[idx] + __logf(fmaxf(acc[r], 1e-6f));
      S[idx] = (_Float16)v;
      float nm = fmaxf(mx[r], v);
      lsum[r] = lsum[r] * __expf(mx[r] - nm) + __expf(v - nm);
      mx[r] = nm;
    }
  }

  // wave-level merge of (mx, lsum)
  int lane = t & 63, wave = t >> 6;
  #pragma unroll
  for (int r = 0; r < 16; r++) {
    float m_ = mx[r], l_ = lsum[r];
    #pragma unroll
    for (int off = 1; off <= 32; off <<= 1) {
      float om = __shfl_xor(m_, off, 64);
      float ol = __shfl_xor(l_, off, 64);
      float nm = fmaxf(m_, om);
      l_ = l_ * __expf(m_ - nm) + ol * __expf(om - nm);
      m_ = nm;
    }
    if (lane == 0) red[r][wave] = make_float2(m_, l_);
  }
  __syncthreads();
  if (t < 16) {
    float2 a = red[t][0];
    #pragma unroll
    for (int w = 1; w < 4; w++) {
      float2 b = red[t][w];
      float nm = fmaxf(a.x, b.x);
      a.y = a.y * __expf(a.x - nm) + b.y * __expf(b.x - nm);
      a.x = nm;
    }
    stats[(t << 10) + n] = a;
  }
}

// ---------------- K4: out[n, r*64+d] = sum_m softmax * V[r,m,d] + f_a ----------------
__global__ __launch_bounds__(256) void pv_kernel(
    const _Float16* __restrict__ S, const float2* __restrict__ stats,
    const float* __restrict__ V, const float* __restrict__ fa,
    float* __restrict__ out) {
  int r = blockIdx.x >> 5;
  int n0 = (blockIdx.x & 31) * 32;
  __shared__ float Pt[64][36];   // [m_local][n_local], padded
  __shared__ float Vt[64][68];   // [m_local][d], padded
  __shared__ float2 st[32];
  int t = threadIdx.x;
  if (t < 32) st[t] = stats[r * NN + n0 + t];

  int d0 = (t & 15) * 4;
  int nl0 = (t >> 4) * 2;
  float acc[2][4] = {};

  for (int m0 = 0; m0 < NN; m0 += 64) {
    __syncthreads();
    // stage P^T = exp(S - mx): thread loads 8 m's of one n-row (16 B fp16)
    {
      int nl = t >> 3;
      int ml = (t & 7) * 8;
      const _Float16* sp = S + ((size_t)r << 20) + ((size_t)(n0 + nl) << 10) + m0 + ml;
      f16x8 sv = *(const f16x8*)sp;
      float mxn = st[nl].x;
      #pragma unroll
      for (int u = 0; u < 8; u++) Pt[ml + u][nl] = __expf((float)sv[u] - mxn);
    }
    // stage V tile
    {
      int ml = t >> 2;
      int dq = (t & 3) * 16;
      const float* vp = V + ((size_t)r * NN + m0 + ml) * DK + dq;
      #pragma unroll
      for (int u = 0; u < 4; u++) {
        float4 vv = ((const float4*)vp)[u];
        *(float4*)&Vt[ml][dq + u * 4] = vv;
      }
    }
    __syncthreads();
    #pragma unroll 8
    for (int ml = 0; ml < 64; ml++) {
      float a0 = Pt[ml][nl0];
      float a1 = Pt[ml][nl0 + 1];
      float4 vv = *(const float4*)&Vt[ml][d0];
      acc[0][0] += a0 * vv.x; acc[0][1] += a0 * vv.y;
      acc[0][2] += a0 * vv.z; acc[0][3] += a0 * vv.w;
      acc[1][0] += a1 * vv.x; acc[1][1] += a1 * vv.y;
      acc[1][2] += a1 * vv.z; acc[1][3] += a1 * vv.w;
    }
  }

  #pragma unroll
  for (int i = 0; i < 2; i++) {
    int n = n0 + nl0 + i;
    float rs = 1.0f / st[nl0 + i].y;
    int col = r * DK + d0;
    const float4 f = *(const float4*)(fa + (size_t)n * DAPP + col);
    float4 o;
    o.x = acc[i][0] * rs + f.x;
    o.y = acc[i][1] * rs + f.y;
    o.z = acc[i][2] * rs + f.z;
    o.w = acc[i][3] * rs + f.w;
    *(float4*)(out + (size_t)n * DAPP + col) = o;
  }
}

// ---------------- launch ----------------
extern "C" void kernel_launch(void* const* d_in, const int* in_sizes, int n_in,
                              void* d_out, int out_size, void* d_ws, size_t ws_size,
                              hipStream_t stream) {
  const float* fa  = (const float*)d_in[0];
  const float* pe  = (const float*)d_in[1];
  const float* WGw = (const float*)d_in[2];
  const float* WGb = (const float*)d_in[3];
  const float* WKw = (const float*)d_in[4];
  const float* WKb = (const float*)d_in[5];
  const float* WQw = (const float*)d_in[6];
  const float* WQb = (const float*)d_in[7];
  const float* WVw = (const float*)d_in[8];
  const float* WVb = (const float*)d_in[9];
  float* out = (float*)d_out;

  char* ws = (char*)d_ws;
  __bf16* fab = (__bf16*)(ws + OFF_FAB);
  __bf16* wb  = (__bf16*)(ws + OFF_WB);
  __bf16* Kb  = (__bf16*)(ws + OFF_KB);
  __bf16* Qb  = (__bf16*)(ws + OFF_QB);
  float*  V   = (float*)(ws + OFF_V);
  _Float16* S = (_Float16*)(ws + OFF_S);
  float2* st  = (float2*)(ws + OFF_ST);

  // K0: cast (4M elems)
  cast_kernel<<<16384, 256, 0, stream>>>(fa, WKw, WQw, WVw, fab, wb);
  // K1: KQV projection (3072 waves = 768 blocks)
  kqv_kernel<<<768, 256, 0, stream>>>(fab, wb, WKb, WQb, WVb, Kb, Qb, V);
  // K2: scores (16384 waves = 4096 blocks), fp16 out
  scores_kernel<<<4096, 256, 0, stream>>>(Kb, Qb, S);
  // K3: fused gate + stats (1024 n-blocks)
  gate_stats_kernel<<<1024, 256, 0, stream>>>(pe, WGw, WGb, S, st);
  // K4: PV + residual (16 r x 32 n-tiles)
  pv_kernel<<<512, 256, 0, stream>>>(S, st, V, fa, out);
}

// Round 3
// 608.332 us; speedup vs baseline: 1.1133x; 1.1133x over previous
//
#include <hip/hip_runtime.h>
#include <hip/hip_bf16.h>
#include <hip/hip_fp16.h>
#include <math.h>

// Problem constants (fixed by the reference)
#define NN 1024      // proposals
#define DAPP 1024    // appearance dim
#define DK 64        // key dim
#define DG 64        // geo dim
#define NR 16        // relations

typedef __bf16 bf16x8 __attribute__((ext_vector_type(8)));
typedef _Float16 f16x8 __attribute__((ext_vector_type(8)));
typedef _Float16 f16x4 __attribute__((ext_vector_type(4)));
typedef float f32x4 __attribute__((ext_vector_type(4)));

// ---------------- ws layout (bytes) ----------------
// fab  : bf16 [1024][1024]        @ OFF_FAB   (2 MB)
// Wb   : bf16 [3][16][64][1024]   @ OFF_WB    (6 MB)   (K,Q,V stacked)
// Kb   : bf16 [16][1024][64]      @ OFF_KB    (2 MB)
// Qb   : bf16 [16][1024][64]      @ OFF_QB    (2 MB)
// V    : f32  [16][1024][64]      @ OFF_V     (4 MB)
// X    : f16  [16][1024][1024]    @ OFF_S     (32 MB)  final logits (score + log-gate)
// stats: f32x2 [16*1024]          @ OFF_ST    (128 KB)
static constexpr size_t OFF_FAB = 0;
static constexpr size_t OFF_WB  = OFF_FAB + (size_t)NN * DAPP * 2;
static constexpr size_t OFF_KB  = OFF_WB + (size_t)3 * NR * DK * DAPP * 2;
static constexpr size_t OFF_QB  = OFF_KB + (size_t)NR * NN * DK * 2;
static constexpr size_t OFF_V   = OFF_QB + (size_t)NR * NN * DK * 2;
static constexpr size_t OFF_S   = OFF_V + (size_t)NR * NN * DK * 4;
static constexpr size_t OFF_ST  = OFF_S + (size_t)NR * NN * NN * 2;

// ---------------- K0: cast f_a and W{K,Q,V} to bf16 ----------------
__global__ __launch_bounds__(256) void cast_kernel(
    const float* __restrict__ fa, const float* __restrict__ wk,
    const float* __restrict__ wq, const float* __restrict__ wv,
    __bf16* __restrict__ fab, __bf16* __restrict__ wb) {
  int i = blockIdx.x * 256 + threadIdx.x;  // 0 .. 4M-1
  const int M1 = NN * DAPP;                // 1M
  if (i < M1) {
    fab[i] = (__bf16)fa[i];
  } else {
    int j = i - M1;                        // 0 .. 3M-1
    int p = j >> 20;
    int o = j & (M1 - 1);
    const float* src = (p == 0) ? wk : ((p == 1) ? wq : wv);
    wb[j] = (__bf16)src[o];
  }
}

// ---------------- K1: KQV projection, bf16 MFMA, fused bias ----------------
__global__ __launch_bounds__(256) void kqv_kernel(
    const __bf16* __restrict__ fab, const __bf16* __restrict__ wb,
    const float* __restrict__ kbias, const float* __restrict__ qbias,
    const float* __restrict__ vbias,
    __bf16* __restrict__ Kb, __bf16* __restrict__ Qb, float* __restrict__ V) {
  int wave = blockIdx.x * 4 + (threadIdx.x >> 6);  // 0..3071
  int l = threadIdx.x & 63;
  int nt = wave / 96;        // 32 n-tiles
  int jt = wave % 96;        // 96 j-tiles
  int n0 = nt * 32, j0 = jt * 32;
  int ra = l & 15;
  int ko = (l >> 4) * 8;

  f32x4 acc[2][2] = {};
  for (int k0 = 0; k0 < DAPP; k0 += 32) {
    bf16x8 a0 = *(const bf16x8*)(fab + (size_t)(n0 + ra) * DAPP + k0 + ko);
    bf16x8 a1 = *(const bf16x8*)(fab + (size_t)(n0 + 16 + ra) * DAPP + k0 + ko);
    bf16x8 b0 = *(const bf16x8*)(wb + (size_t)(j0 + ra) * DAPP + k0 + ko);
    bf16x8 b1 = *(const bf16x8*)(wb + (size_t)(j0 + 16 + ra) * DAPP + k0 + ko);
    acc[0][0] = __builtin_amdgcn_mfma_f32_16x16x32_bf16(a0, b0, acc[0][0], 0, 0, 0);
    acc[0][1] = __builtin_amdgcn_mfma_f32_16x16x32_bf16(a0, b1, acc[0][1], 0, 0, 0);
    acc[1][0] = __builtin_amdgcn_mfma_f32_16x16x32_bf16(a1, b0, acc[1][0], 0, 0, 0);
    acc[1][1] = __builtin_amdgcn_mfma_f32_16x16x32_bf16(a1, b1, acc[1][1], 0, 0, 0);
  }

  // C/D layout: col = lane&15, row = (lane>>4)*4 + reg
  #pragma unroll
  for (int i = 0; i < 2; i++) {
    #pragma unroll
    for (int jj = 0; jj < 2; jj++) {
      #pragma unroll
      for (int q = 0; q < 4; q++) {
        int n = n0 + i * 16 + (l >> 4) * 4 + q;
        int col = j0 + jj * 16 + (l & 15);
        int proj = col >> 10;
        int rd = col & 1023;          // r*64 + d
        int r = rd >> 6, d = rd & 63;
        float v = acc[i][jj][q];
        size_t oidx = ((size_t)r * NN + n) * DK + d;
        if (proj == 0)      Kb[oidx] = (__bf16)(v + kbias[rd]);
        else if (proj == 1) Qb[oidx] = (__bf16)(v + qbias[rd]);
        else                V[oidx] = v + vbias[rd];
      }
    }
  }
}

// ---------------- K2: FUSED gate + scores -> X (fp16) ----------------
// block: 16-n-tile x 128-m-chunk, all 16 r. grid = 64*8 = 512.
// Phase 1 (per 32-m subtile): stream pe (fp32), gate dot in fp32 (log-clip
// precision), log -> LDS (fp16). Phase 2: score MFMA (A=Q rows m, B=K rows n
// => D[row=m][col=n], lane's 4 acc = 4 consecutive m), add lg, store 8B fp16.
__global__ __launch_bounds__(256) void gate_score_kernel(
    const float* __restrict__ pe, const float* __restrict__ WGw,
    const float* __restrict__ WGb,
    const __bf16* __restrict__ Kb, const __bf16* __restrict__ Qb,
    _Float16* __restrict__ X) {
  __shared__ float4 wgt[16][16];      // [g4][r]
  __shared__ float wgb[16];
  __shared__ _Float16 lg[16][16][36]; // [r][n_local][m_local], padded to 36 (18KB)
  int t = threadIdx.x;
  int nt = blockIdx.x >> 3, mc = blockIdx.x & 7;
  int n0 = nt * 16, m0 = mc * 128;
  {
    int g4 = t >> 4, r = t & 15;
    wgt[g4][r] = ((const float4*)WGw)[r * 16 + g4];
    if (t < 16) wgb[t] = WGb[t];
  }
  int l = t & 63, w = t >> 6;   // lane, wave(0..3)
  int rb = w * 4;               // this wave's relations rb..rb+3
  int ra = l & 15;
  int ko = (l >> 4) * 8;

  // preload K fragments (B operand: rows = n) for 4 r's x 2 k-steps
  bf16x8 kf[4][2];
  #pragma unroll
  for (int rr = 0; rr < 4; rr++)
    #pragma unroll
    for (int kk = 0; kk < 2; kk++)
      kf[rr][kk] = *(const bf16x8*)(Kb + (((size_t)(rb + rr) << 10) + n0 + ra) * DK + kk * 32 + ko);
  __syncthreads();

  for (int ms = 0; ms < 4; ms++) {
    // ---- phase 1: gate for 16n x 32m (512 pairs, 2 per thread) ----
    #pragma unroll
    for (int pp = 0; pp < 2; pp++) {
      int p = t + pp * 256;
      int n = p >> 5, ml = p & 31;
      const float4* pe4 = (const float4*)(pe + (((size_t)(n0 + n) << 10) + m0 + ms * 32 + ml) * DG);
      float acc[16];
      #pragma unroll
      for (int r = 0; r < 16; r++) acc[r] = wgb[r];
      #pragma unroll
      for (int g4 = 0; g4 < 16; g4++) {
        float4 pv = pe4[g4];
        #pragma unroll
        for (int r = 0; r < 16; r++) {
          float4 wv = wgt[g4][r];
          acc[r] = fmaf(pv.x, wv.x, fmaf(pv.y, wv.y, fmaf(pv.z, wv.z, fmaf(pv.w, wv.w, acc[r]))));
        }
      }
      #pragma unroll
      for (int r = 0; r < 16; r++)
        lg[r][n][ml] = (_Float16)__logf(fmaxf(acc[r], 1e-6f));
    }
    __syncthreads();
    // ---- phase 2: scores + combine + store, this wave's 4 r's ----
    #pragma unroll
    for (int rr = 0; rr < 4; rr++) {
      int r = rb + rr;
      const __bf16* Qr = Qb + (((size_t)r << 10)) * DK;
      #pragma unroll
      for (int mt = 0; mt < 2; mt++) {
        int mbase = m0 + ms * 32 + mt * 16;
        f32x4 acc2 = {};
        #pragma unroll
        for (int kk = 0; kk < 2; kk++) {
          bf16x8 qa = *(const bf16x8*)(Qr + (size_t)(mbase + ra) * DK + kk * 32 + ko);
          acc2 = __builtin_amdgcn_mfma_f32_16x16x32_bf16(qa, kf[rr][kk], acc2, 0, 0, 0);
        }
        // lane holds D[row=m][col=n]: n = ra, m = mbase + (l>>4)*4 + q
        f16x4 lgv = *(const f16x4*)&lg[r][ra][mt * 16 + ((l >> 4) << 2)];
        f16x4 xv;
        #pragma unroll
        for (int q = 0; q < 4; q++)
          xv[q] = (_Float16)(acc2[q] * 0.125f + (float)lgv[q]);
        *(f16x4*)(X + ((size_t)r << 20) + ((size_t)(n0 + ra) << 10) + mbase + ((l >> 4) << 2)) = xv;
      }
    }
    __syncthreads();  // protect lg before next gate phase
  }
}

// ---------------- K3: per-(r,n) row max and sum-exp over X ----------------
__global__ __launch_bounds__(256) void stats_kernel(
    const _Float16* __restrict__ X, float2* __restrict__ stats) {
  int row = blockIdx.x * 4 + (threadIdx.x >> 6);  // 0..16383 = r*1024+n
  int l = threadIdx.x & 63;
  const f16x8* Sp = (const f16x8*)(X + ((size_t)row << 10) + l * 16);
  f16x8 a = Sp[0], b = Sp[1];
  float v[16];
  float mx = -1e30f;
  #pragma unroll
  for (int i = 0; i < 8; i++) { v[i] = (float)a[i]; v[8 + i] = (float)b[i]; }
  #pragma unroll
  for (int i = 0; i < 16; i++) mx = fmaxf(mx, v[i]);
  #pragma unroll
  for (int off = 32; off >= 1; off >>= 1) mx = fmaxf(mx, __shfl_xor(mx, off, 64));
  float sm = 0.f;
  #pragma unroll
  for (int i = 0; i < 16; i++) sm += __expf(v[i] - mx);
  #pragma unroll
  for (int off = 32; off >= 1; off >>= 1) sm += __shfl_xor(sm, off, 64);
  if (l == 0) stats[row] = make_float2(mx, sm);
}

// ---------------- K4: out[n, r*64+d] = sum_m softmax * V[r,m,d] + f_a ----------------
__global__ __launch_bounds__(256) void pv_kernel(
    const _Float16* __restrict__ S, const float2* __restrict__ stats,
    const float* __restrict__ V, const float* __restrict__ fa,
    float* __restrict__ out) {
  int r = blockIdx.x >> 5;
  int n0 = (blockIdx.x & 31) * 32;
  __shared__ float Pt[64][36];   // [m_local][n_local], padded
  __shared__ float Vt[64][68];   // [m_local][d], padded
  __shared__ float2 st[32];
  int t = threadIdx.x;
  if (t < 32) st[t] = stats[r * NN + n0 + t];

  int d0 = (t & 15) * 4;
  int nl0 = (t >> 4) * 2;
  float acc[2][4] = {};

  for (int m0 = 0; m0 < NN; m0 += 64) {
    __syncthreads();
    {
      int nl = t >> 3;
      int ml = (t & 7) * 8;
      const _Float16* sp = S + ((size_t)r << 20) + ((size_t)(n0 + nl) << 10) + m0 + ml;
      f16x8 sv = *(const f16x8*)sp;
      float mxn = st[nl].x;
      #pragma unroll
      for (int u = 0; u < 8; u++) Pt[ml + u][nl] = __expf((float)sv[u] - mxn);
    }
    {
      int ml = t >> 2;
      int dq = (t & 3) * 16;
      const float* vp = V + ((size_t)r * NN + m0 + ml) * DK + dq;
      #pragma unroll
      for (int u = 0; u < 4; u++) {
        float4 vv = ((const float4*)vp)[u];
        *(float4*)&Vt[ml][dq + u * 4] = vv;
      }
    }
    __syncthreads();
    #pragma unroll 8
    for (int ml = 0; ml < 64; ml++) {
      float a0 = Pt[ml][nl0];
      float a1 = Pt[ml][nl0 + 1];
      float4 vv = *(const float4*)&Vt[ml][d0];
      acc[0][0] += a0 * vv.x; acc[0][1] += a0 * vv.y;
      acc[0][2] += a0 * vv.z; acc[0][3] += a0 * vv.w;
      acc[1][0] += a1 * vv.x; acc[1][1] += a1 * vv.y;
      acc[1][2] += a1 * vv.z; acc[1][3] += a1 * vv.w;
    }
  }

  #pragma unroll
  for (int i = 0; i < 2; i++) {
    int n = n0 + nl0 + i;
    float rs = 1.0f / st[nl0 + i].y;
    int col = r * DK + d0;
    const float4 f = *(const float4*)(fa + (size_t)n * DAPP + col);
    float4 o;
    o.x = acc[i][0] * rs + f.x;
    o.y = acc[i][1] * rs + f.y;
    o.z = acc[i][2] * rs + f.z;
    o.w = acc[i][3] * rs + f.w;
    *(float4*)(out + (size_t)n * DAPP + col) = o;
  }
}

// ---------------- launch ----------------
extern "C" void kernel_launch(void* const* d_in, const int* in_sizes, int n_in,
                              void* d_out, int out_size, void* d_ws, size_t ws_size,
                              hipStream_t stream) {
  const float* fa  = (const float*)d_in[0];
  const float* pe  = (const float*)d_in[1];
  const float* WGw = (const float*)d_in[2];
  const float* WGb = (const float*)d_in[3];
  const float* WKw = (const float*)d_in[4];
  const float* WKb = (const float*)d_in[5];
  const float* WQw = (const float*)d_in[6];
  const float* WQb = (const float*)d_in[7];
  const float* WVw = (const float*)d_in[8];
  const float* WVb = (const float*)d_in[9];
  float* out = (float*)d_out;

  char* ws = (char*)d_ws;
  __bf16* fab = (__bf16*)(ws + OFF_FAB);
  __bf16* wb  = (__bf16*)(ws + OFF_WB);
  __bf16* Kb  = (__bf16*)(ws + OFF_KB);
  __bf16* Qb  = (__bf16*)(ws + OFF_QB);
  float*  V   = (float*)(ws + OFF_V);
  _Float16* X = (_Float16*)(ws + OFF_S);
  float2* st  = (float2*)(ws + OFF_ST);

  // K0: cast (4M elems)
  cast_kernel<<<16384, 256, 0, stream>>>(fa, WKw, WQw, WVw, fab, wb);
  // K1: KQV projection
  kqv_kernel<<<768, 256, 0, stream>>>(fab, wb, WKb, WQb, WVb, Kb, Qb, V);
  // K2: fused gate + scores -> X  (64 n-tiles x 8 m-chunks)
  gate_score_kernel<<<512, 256, 0, stream>>>(pe, WGw, WGb, Kb, Qb, X);
  // K3: stats (16384 rows, 4/block)
  stats_kernel<<<4096, 256, 0, stream>>>(X, st);
  // K4: PV + residual
  pv_kernel<<<512, 256, 0, stream>>>(X, st, V, fa, out);
}

// Round 4
// 568.672 us; speedup vs baseline: 1.1910x; 1.0697x over previous
//
#include <hip/hip_runtime.h>
#include <hip/hip_bf16.h>
#include <hip/hip_fp16.h>
#include <math.h>

// Problem constants (fixed by the reference)
#define NN 1024      // proposals
#define DAPP 1024    // appearance dim
#define DK 64        // key dim
#define DG 64        // geo dim
#define NR 16        // relations

typedef __bf16 bf16x8 __attribute__((ext_vector_type(8)));
typedef _Float16 f16x8 __attribute__((ext_vector_type(8)));
typedef _Float16 f16x4 __attribute__((ext_vector_type(4)));
typedef float f32x4 __attribute__((ext_vector_type(4)));

// ---------------- ws layout (bytes) ----------------
static constexpr size_t OFF_FAB = 0;
static constexpr size_t OFF_WB  = OFF_FAB + (size_t)NN * DAPP * 2;
static constexpr size_t OFF_KB  = OFF_WB + (size_t)3 * NR * DK * DAPP * 2;
static constexpr size_t OFF_QB  = OFF_KB + (size_t)NR * NN * DK * 2;
static constexpr size_t OFF_V   = OFF_QB + (size_t)NR * NN * DK * 2;
static constexpr size_t OFF_S   = OFF_V + (size_t)NR * NN * DK * 4;
static constexpr size_t OFF_ST  = OFF_S + (size_t)NR * NN * NN * 2;

// ---------------- K0: cast f_a and W{K,Q,V} to bf16 ----------------
__global__ __launch_bounds__(256) void cast_kernel(
    const float* __restrict__ fa, const float* __restrict__ wk,
    const float* __restrict__ wq, const float* __restrict__ wv,
    __bf16* __restrict__ fab, __bf16* __restrict__ wb) {
  int i = blockIdx.x * 256 + threadIdx.x;  // 0 .. 4M-1
  const int M1 = NN * DAPP;                // 1M
  if (i < M1) {
    fab[i] = (__bf16)fa[i];
  } else {
    int j = i - M1;                        // 0 .. 3M-1
    int p = j >> 20;
    int o = j & (M1 - 1);
    const float* src = (p == 0) ? wk : ((p == 1) ? wq : wv);
    wb[j] = (__bf16)src[o];
  }
}

// ---------------- K1: KQV projection, bf16 MFMA, fused bias ----------------
__global__ __launch_bounds__(256) void kqv_kernel(
    const __bf16* __restrict__ fab, const __bf16* __restrict__ wb,
    const float* __restrict__ kbias, const float* __restrict__ qbias,
    const float* __restrict__ vbias,
    __bf16* __restrict__ Kb, __bf16* __restrict__ Qb, float* __restrict__ V) {
  int wave = blockIdx.x * 4 + (threadIdx.x >> 6);  // 0..3071
  int l = threadIdx.x & 63;
  int nt = wave / 96;        // 32 n-tiles
  int jt = wave % 96;        // 96 j-tiles
  int n0 = nt * 32, j0 = jt * 32;
  int ra = l & 15;
  int ko = (l >> 4) * 8;

  f32x4 acc[2][2] = {};
  for (int k0 = 0; k0 < DAPP; k0 += 32) {
    bf16x8 a0 = *(const bf16x8*)(fab + (size_t)(n0 + ra) * DAPP + k0 + ko);
    bf16x8 a1 = *(const bf16x8*)(fab + (size_t)(n0 + 16 + ra) * DAPP + k0 + ko);
    bf16x8 b0 = *(const bf16x8*)(wb + (size_t)(j0 + ra) * DAPP + k0 + ko);
    bf16x8 b1 = *(const bf16x8*)(wb + (size_t)(j0 + 16 + ra) * DAPP + k0 + ko);
    acc[0][0] = __builtin_amdgcn_mfma_f32_16x16x32_bf16(a0, b0, acc[0][0], 0, 0, 0);
    acc[0][1] = __builtin_amdgcn_mfma_f32_16x16x32_bf16(a0, b1, acc[0][1], 0, 0, 0);
    acc[1][0] = __builtin_amdgcn_mfma_f32_16x16x32_bf16(a1, b0, acc[1][0], 0, 0, 0);
    acc[1][1] = __builtin_amdgcn_mfma_f32_16x16x32_bf16(a1, b1, acc[1][1], 0, 0, 0);
  }

  // C/D layout: col = lane&15, row = (lane>>4)*4 + reg
  #pragma unroll
  for (int i = 0; i < 2; i++) {
    #pragma unroll
    for (int jj = 0; jj < 2; jj++) {
      #pragma unroll
      for (int q = 0; q < 4; q++) {
        int n = n0 + i * 16 + (l >> 4) * 4 + q;
        int col = j0 + jj * 16 + (l & 15);
        int proj = col >> 10;
        int rd = col & 1023;          // r*64 + d
        int r = rd >> 6, d = rd & 63;
        float v = acc[i][jj][q];
        size_t oidx = ((size_t)r * NN + n) * DK + d;
        if (proj == 0)      Kb[oidx] = (__bf16)(v + kbias[rd]);
        else if (proj == 1) Qb[oidx] = (__bf16)(v + qbias[rd]);
        else                V[oidx] = v + vbias[rd];
      }
    }
  }
}

// ---------------- K2: FUSED gate + scores -> X (fp16) ----------------
// block: 16-n-tile x 32-m-chunk, all 16 r. grid = 64*32 = 2048 (8 blocks/CU
// dispatchable -> latency hiding; R3's 512-block version was latency-bound
// at 11% occupancy).
// Phase 1: stream pe (fp32), gate dot in fp32 (log-clip precision), log ->
// LDS fp16. Phase 2: score MFMA (A=Q rows m, B=K rows n => D[row=m][col=n],
// lane's 4 acc = 4 consecutive m), add lg, store 8B fp16.
__global__ __launch_bounds__(256) void gate_score_kernel(
    const float* __restrict__ pe, const float* __restrict__ WGw,
    const float* __restrict__ WGb,
    const __bf16* __restrict__ Kb, const __bf16* __restrict__ Qb,
    _Float16* __restrict__ X) {
  __shared__ float4 wgt[16][16];      // [g4][r]
  __shared__ float wgb[16];
  __shared__ _Float16 lg[16][16][36]; // [r][n_local][m_local], padded (18KB)
  int t = threadIdx.x;
  int nt = blockIdx.x >> 5, mc = blockIdx.x & 31;
  int n0 = nt * 16, m0 = mc * 32;
  {
    int g4 = t >> 4, r = t & 15;
    wgt[g4][r] = ((const float4*)WGw)[r * 16 + g4];
    if (t < 16) wgb[t] = WGb[t];
  }
  int l = t & 63, w = t >> 6;   // lane, wave(0..3)
  int rb = w * 4;               // this wave's relations rb..rb+3
  int ra = l & 15;
  int ko = (l >> 4) * 8;

  // preload K fragments (B operand: rows = n) for 4 r's x 2 k-steps
  bf16x8 kf[4][2];
  #pragma unroll
  for (int rr = 0; rr < 4; rr++)
    #pragma unroll
    for (int kk = 0; kk < 2; kk++)
      kf[rr][kk] = *(const bf16x8*)(Kb + (((size_t)(rb + rr) << 10) + n0 + ra) * DK + kk * 32 + ko);
  __syncthreads();

  // ---- phase 1: gate for 16n x 32m (512 pairs, 2 per thread) ----
  #pragma unroll
  for (int pp = 0; pp < 2; pp++) {
    int p = t + pp * 256;
    int n = p >> 5, ml = p & 31;
    const float4* pe4 = (const float4*)(pe + (((size_t)(n0 + n) << 10) + m0 + ml) * DG);
    float acc[16];
    #pragma unroll
    for (int r = 0; r < 16; r++) acc[r] = wgb[r];
    #pragma unroll
    for (int g4 = 0; g4 < 16; g4++) {
      float4 pv = pe4[g4];
      #pragma unroll
      for (int r = 0; r < 16; r++) {
        float4 wv = wgt[g4][r];
        acc[r] = fmaf(pv.x, wv.x, fmaf(pv.y, wv.y, fmaf(pv.z, wv.z, fmaf(pv.w, wv.w, acc[r]))));
      }
    }
    #pragma unroll
    for (int r = 0; r < 16; r++)
      lg[r][n][ml] = (_Float16)__logf(fmaxf(acc[r], 1e-6f));
  }
  __syncthreads();

  // ---- phase 2: scores + combine + store, this wave's 4 r's ----
  #pragma unroll
  for (int rr = 0; rr < 4; rr++) {
    int r = rb + rr;
    const __bf16* Qr = Qb + (((size_t)r << 10)) * DK;
    #pragma unroll
    for (int mt = 0; mt < 2; mt++) {
      int mbase = m0 + mt * 16;
      f32x4 acc2 = {};
      #pragma unroll
      for (int kk = 0; kk < 2; kk++) {
        bf16x8 qa = *(const bf16x8*)(Qr + (size_t)(mbase + ra) * DK + kk * 32 + ko);
        acc2 = __builtin_amdgcn_mfma_f32_16x16x32_bf16(qa, kf[rr][kk], acc2, 0, 0, 0);
      }
      // lane holds D[row=m][col=n]: n = ra, m = mbase + (l>>4)*4 + q
      f16x4 lgv = *(const f16x4*)&lg[r][ra][mt * 16 + ((l >> 4) << 2)];
      f16x4 xv;
      #pragma unroll
      for (int q = 0; q < 4; q++)
        xv[q] = (_Float16)(acc2[q] * 0.125f + (float)lgv[q]);
      *(f16x4*)(X + ((size_t)r << 20) + ((size_t)(n0 + ra) << 10) + mbase + ((l >> 4) << 2)) = xv;
    }
  }
}

// ---------------- K3: per-(r,n) row max and sum-exp over X ----------------
__global__ __launch_bounds__(256) void stats_kernel(
    const _Float16* __restrict__ X, float2* __restrict__ stats) {
  int row = blockIdx.x * 4 + (threadIdx.x >> 6);  // 0..16383 = r*1024+n
  int l = threadIdx.x & 63;
  const f16x8* Sp = (const f16x8*)(X + ((size_t)row << 10) + l * 16);
  f16x8 a = Sp[0], b = Sp[1];
  float v[16];
  float mx = -1e30f;
  #pragma unroll
  for (int i = 0; i < 8; i++) { v[i] = (float)a[i]; v[8 + i] = (float)b[i]; }
  #pragma unroll
  for (int i = 0; i < 16; i++) mx = fmaxf(mx, v[i]);
  #pragma unroll
  for (int off = 32; off >= 1; off >>= 1) mx = fmaxf(mx, __shfl_xor(mx, off, 64));
  float sm = 0.f;
  #pragma unroll
  for (int i = 0; i < 16; i++) sm += __expf(v[i] - mx);
  #pragma unroll
  for (int off = 32; off >= 1; off >>= 1) sm += __shfl_xor(sm, off, 64);
  if (l == 0) stats[row] = make_float2(mx, sm);
}

// ---------------- K4: out[n, r*64+d] = sum_m softmax * V[r,m,d] + f_a ----------------
__global__ __launch_bounds__(256) void pv_kernel(
    const _Float16* __restrict__ S, const float2* __restrict__ stats,
    const float* __restrict__ V, const float* __restrict__ fa,
    float* __restrict__ out) {
  int r = blockIdx.x >> 5;
  int n0 = (blockIdx.x & 31) * 32;
  __shared__ float Pt[64][36];   // [m_local][n_local], padded
  __shared__ float Vt[64][68];   // [m_local][d], padded
  __shared__ float2 st[32];
  int t = threadIdx.x;
  if (t < 32) st[t] = stats[r * NN + n0 + t];

  int d0 = (t & 15) * 4;
  int nl0 = (t >> 4) * 2;
  float acc[2][4] = {};

  for (int m0 = 0; m0 < NN; m0 += 64) {
    __syncthreads();
    {
      int nl = t >> 3;
      int ml = (t & 7) * 8;
      const _Float16* sp = S + ((size_t)r << 20) + ((size_t)(n0 + nl) << 10) + m0 + ml;
      f16x8 sv = *(const f16x8*)sp;
      float mxn = st[nl].x;
      #pragma unroll
      for (int u = 0; u < 8; u++) Pt[ml + u][nl] = __expf((float)sv[u] - mxn);
    }
    {
      int ml = t >> 2;
      int dq = (t & 3) * 16;
      const float* vp = V + ((size_t)r * NN + m0 + ml) * DK + dq;
      #pragma unroll
      for (int u = 0; u < 4; u++) {
        float4 vv = ((const float4*)vp)[u];
        *(float4*)&Vt[ml][dq + u * 4] = vv;
      }
    }
    __syncthreads();
    #pragma unroll 8
    for (int ml = 0; ml < 64; ml++) {
      float a0 = Pt[ml][nl0];
      float a1 = Pt[ml][nl0 + 1];
      float4 vv = *(const float4*)&Vt[ml][d0];
      acc[0][0] += a0 * vv.x; acc[0][1] += a0 * vv.y;
      acc[0][2] += a0 * vv.z; acc[0][3] += a0 * vv.w;
      acc[1][0] += a1 * vv.x; acc[1][1] += a1 * vv.y;
      acc[1][2] += a1 * vv.z; acc[1][3] += a1 * vv.w;
    }
  }

  #pragma unroll
  for (int i = 0; i < 2; i++) {
    int n = n0 + nl0 + i;
    float rs = 1.0f / st[nl0 + i].y;
    int col = r * DK + d0;
    const float4 f = *(const float4*)(fa + (size_t)n * DAPP + col);
    float4 o;
    o.x = acc[i][0] * rs + f.x;
    o.y = acc[i][1] * rs + f.y;
    o.z = acc[i][2] * rs + f.z;
    o.w = acc[i][3] * rs + f.w;
    *(float4*)(out + (size_t)n * DAPP + col) = o;
  }
}

// ---------------- launch ----------------
extern "C" void kernel_launch(void* const* d_in, const int* in_sizes, int n_in,
                              void* d_out, int out_size, void* d_ws, size_t ws_size,
                              hipStream_t stream) {
  const float* fa  = (const float*)d_in[0];
  const float* pe  = (const float*)d_in[1];
  const float* WGw = (const float*)d_in[2];
  const float* WGb = (const float*)d_in[3];
  const float* WKw = (const float*)d_in[4];
  const float* WKb = (const float*)d_in[5];
  const float* WQw = (const float*)d_in[6];
  const float* WQb = (const float*)d_in[7];
  const float* WVw = (const float*)d_in[8];
  const float* WVb = (const float*)d_in[9];
  float* out = (float*)d_out;

  char* ws = (char*)d_ws;
  __bf16* fab = (__bf16*)(ws + OFF_FAB);
  __bf16* wb  = (__bf16*)(ws + OFF_WB);
  __bf16* Kb  = (__bf16*)(ws + OFF_KB);
  __bf16* Qb  = (__bf16*)(ws + OFF_QB);
  float*  V   = (float*)(ws + OFF_V);
  _Float16* X = (_Float16*)(ws + OFF_S);
  float2* st  = (float2*)(ws + OFF_ST);

  // K0: cast (4M elems)
  cast_kernel<<<16384, 256, 0, stream>>>(fa, WKw, WQw, WVw, fab, wb);
  // K1: KQV projection
  kqv_kernel<<<768, 256, 0, stream>>>(fab, wb, WKb, WQb, WVb, Kb, Qb, V);
  // K2: fused gate + scores -> X  (64 n-tiles x 32 m-chunks = 2048 blocks)
  gate_score_kernel<<<2048, 256, 0, stream>>>(pe, WGw, WGb, Kb, Qb, X);
  // K3: stats (16384 rows, 4/block)
  stats_kernel<<<4096, 256, 0, stream>>>(X, st);
  // K4: PV + residual
  pv_kernel<<<512, 256, 0, stream>>>(X, st, V, fa, out);
}

// Round 5
// 518.044 us; speedup vs baseline: 1.3074x; 1.0977x over previous
//
#include <hip/hip_runtime.h>
#include <hip/hip_bf16.h>
#include <hip/hip_fp16.h>
#include <math.h>

// Problem constants (fixed by the reference)
#define NN 1024      // proposals
#define DAPP 1024    // appearance dim
#define DK 64        // key dim
#define DG 64        // geo dim
#define NR 16        // relations

typedef __bf16 bf16x8 __attribute__((ext_vector_type(8)));
typedef _Float16 f16x8 __attribute__((ext_vector_type(8)));
typedef _Float16 f16x4 __attribute__((ext_vector_type(4)));
typedef float f32x4 __attribute__((ext_vector_type(4)));

// ---------------- ws layout (bytes) ----------------
static constexpr size_t OFF_FAB = 0;
static constexpr size_t OFF_WB  = OFF_FAB + (size_t)NN * DAPP * 2;
static constexpr size_t OFF_KB  = OFF_WB + (size_t)3 * NR * DK * DAPP * 2;
static constexpr size_t OFF_QB  = OFF_KB + (size_t)NR * NN * DK * 2;
static constexpr size_t OFF_V   = OFF_QB + (size_t)NR * NN * DK * 2;
static constexpr size_t OFF_S   = OFF_V + (size_t)NR * NN * DK * 4;
static constexpr size_t OFF_ST  = OFF_S + (size_t)NR * NN * NN * 2;

// ---------------- K0: cast f_a and W{K,Q,V} to bf16 ----------------
__global__ __launch_bounds__(256) void cast_kernel(
    const float* __restrict__ fa, const float* __restrict__ wk,
    const float* __restrict__ wq, const float* __restrict__ wv,
    __bf16* __restrict__ fab, __bf16* __restrict__ wb) {
  int i = blockIdx.x * 256 + threadIdx.x;  // 0 .. 4M-1
  const int M1 = NN * DAPP;                // 1M
  if (i < M1) {
    fab[i] = (__bf16)fa[i];
  } else {
    int j = i - M1;                        // 0 .. 3M-1
    int p = j >> 20;
    int o = j & (M1 - 1);
    const float* src = (p == 0) ? wk : ((p == 1) ? wq : wv);
    wb[j] = (__bf16)src[o];
  }
}

// ---------------- K1: KQV projection, bf16 MFMA, fused bias ----------------
__global__ __launch_bounds__(256) void kqv_kernel(
    const __bf16* __restrict__ fab, const __bf16* __restrict__ wb,
    const float* __restrict__ kbias, const float* __restrict__ qbias,
    const float* __restrict__ vbias,
    __bf16* __restrict__ Kb, __bf16* __restrict__ Qb, float* __restrict__ V) {
  int wave = blockIdx.x * 4 + (threadIdx.x >> 6);  // 0..3071
  int l = threadIdx.x & 63;
  int nt = wave / 96;        // 32 n-tiles
  int jt = wave % 96;        // 96 j-tiles
  int n0 = nt * 32, j0 = jt * 32;
  int ra = l & 15;
  int ko = (l >> 4) * 8;

  f32x4 acc[2][2] = {};
  for (int k0 = 0; k0 < DAPP; k0 += 32) {
    bf16x8 a0 = *(const bf16x8*)(fab + (size_t)(n0 + ra) * DAPP + k0 + ko);
    bf16x8 a1 = *(const bf16x8*)(fab + (size_t)(n0 + 16 + ra) * DAPP + k0 + ko);
    bf16x8 b0 = *(const bf16x8*)(wb + (size_t)(j0 + ra) * DAPP + k0 + ko);
    bf16x8 b1 = *(const bf16x8*)(wb + (size_t)(j0 + 16 + ra) * DAPP + k0 + ko);
    acc[0][0] = __builtin_amdgcn_mfma_f32_16x16x32_bf16(a0, b0, acc[0][0], 0, 0, 0);
    acc[0][1] = __builtin_amdgcn_mfma_f32_16x16x32_bf16(a0, b1, acc[0][1], 0, 0, 0);
    acc[1][0] = __builtin_amdgcn_mfma_f32_16x16x32_bf16(a1, b0, acc[1][0], 0, 0, 0);
    acc[1][1] = __builtin_amdgcn_mfma_f32_16x16x32_bf16(a1, b1, acc[1][1], 0, 0, 0);
  }

  // C/D layout: col = lane&15, row = (lane>>4)*4 + reg
  #pragma unroll
  for (int i = 0; i < 2; i++) {
    #pragma unroll
    for (int jj = 0; jj < 2; jj++) {
      #pragma unroll
      for (int q = 0; q < 4; q++) {
        int n = n0 + i * 16 + (l >> 4) * 4 + q;
        int col = j0 + jj * 16 + (l & 15);
        int proj = col >> 10;
        int rd = col & 1023;          // r*64 + d
        int r = rd >> 6, d = rd & 63;
        float v = acc[i][jj][q];
        size_t oidx = ((size_t)r * NN + n) * DK + d;
        if (proj == 0)      Kb[oidx] = (__bf16)(v + kbias[rd]);
        else if (proj == 1) Qb[oidx] = (__bf16)(v + qbias[rd]);
        else                V[oidx] = v + vbias[rd];
      }
    }
  }
}

// ---------------- K2: FUSED gate(MFMA) + scores -> X (fp16) ----------------
// One independent wave-job per 16n x 16m tile (all 16 r). 4096 jobs =
// 1024 blocks x 4 waves, NO barriers.
// Gate: A = pe points (16 m for fixed n), fp32 loads (coalesced: each
// dwordx4 inst covers 16 points x 64B = 16 full lines), cvt->bf16, MFMA
// vs register WG frags; bias+relu+clip+log in fp32 -> lg in LDS (fp16).
// Score: A=Q(m) B=K(n) MFMA => D[row=m][col=n]; X = score*0.125 + lg.
__global__ __launch_bounds__(256) void gate_score_kernel(
    const float* __restrict__ pe, const float* __restrict__ WGw,
    const float* __restrict__ WGb,
    const __bf16* __restrict__ Kb, const __bf16* __restrict__ Qb,
    _Float16* __restrict__ X) {
  // per-wave lg slice: [r][n][m], n padded to 17, m padded to 20
  // (8B-aligned rows, <=2-way bank aliasing on b64 ops)
  __shared__ alignas(16) _Float16 lg[4][16][17][20];
  int t = threadIdx.x;
  int l = t & 63, w = t >> 6;
  int job = blockIdx.x * 4 + w;
  int nt = job >> 6, mt = job & 63;
  int n0 = nt * 16, m0 = mt * 16;
  int pr = l & 15;            // A-row / B-col selector
  int kg = (l >> 4) * 8;      // k-offset within frag
  int mq = (l >> 4) << 2;     // D row quad base

  // WG B-frags (fp32 -> bf16), col = r = pr
  bf16x8 wgf[2];
  #pragma unroll
  for (int f = 0; f < 2; f++) {
    const float* wp = WGw + pr * DG + f * 32 + kg;
    float4 a = *(const float4*)wp;
    float4 b = *(const float4*)(wp + 4);
    bf16x8 v;
    v[0] = (__bf16)a.x; v[1] = (__bf16)a.y; v[2] = (__bf16)a.z; v[3] = (__bf16)a.w;
    v[4] = (__bf16)b.x; v[5] = (__bf16)b.y; v[6] = (__bf16)b.z; v[7] = (__bf16)b.w;
    wgf[f] = v;
  }
  float biasr = WGb[pr];

  // ---- gate: 16 n, 2 MFMA each ----
  #pragma unroll 4
  for (int nl = 0; nl < 16; nl++) {
    const float* pp = pe + (((size_t)(n0 + nl) << 10) + m0 + pr) * DG + kg;
    f32x4 acc = {};
    #pragma unroll
    for (int f = 0; f < 2; f++) {
      float4 a = *(const float4*)(pp + f * 32);
      float4 b = *(const float4*)(pp + f * 32 + 4);
      bf16x8 av;
      av[0] = (__bf16)a.x; av[1] = (__bf16)a.y; av[2] = (__bf16)a.z; av[3] = (__bf16)a.w;
      av[4] = (__bf16)b.x; av[5] = (__bf16)b.y; av[6] = (__bf16)b.z; av[7] = (__bf16)b.w;
      acc = __builtin_amdgcn_mfma_f32_16x16x32_bf16(av, wgf[f], acc, 0, 0, 0);
    }
    // D: col = r = pr, row = m-local = mq + q
    f16x4 ov;
    #pragma unroll
    for (int q = 0; q < 4; q++)
      ov[q] = (_Float16)__logf(fmaxf(acc[q] + biasr, 1e-6f));
    *(f16x4*)&lg[w][pr][nl][mq] = ov;
  }

  // ---- score: 16 r, 2 MFMA each; combine with lg; store X ----
  #pragma unroll 4
  for (int r = 0; r < 16; r++) {
    const __bf16* Kr = Kb + (((size_t)r << 10)) * DK;
    const __bf16* Qr = Qb + (((size_t)r << 10)) * DK;
    f32x4 acc = {};
    #pragma unroll
    for (int f = 0; f < 2; f++) {
      bf16x8 qa = *(const bf16x8*)(Qr + (size_t)(m0 + pr) * DK + f * 32 + kg);
      bf16x8 kb = *(const bf16x8*)(Kr + (size_t)(n0 + pr) * DK + f * 32 + kg);
      acc = __builtin_amdgcn_mfma_f32_16x16x32_bf16(qa, kb, acc, 0, 0, 0);
    }
    // D: col = n-local = pr, row = m-local = mq + q
    f16x4 lgv = *(const f16x4*)&lg[w][r][pr][mq];
    f16x4 xv;
    #pragma unroll
    for (int q = 0; q < 4; q++)
      xv[q] = (_Float16)(acc[q] * 0.125f + (float)lgv[q]);
    *(f16x4*)(X + ((size_t)r << 20) + ((size_t)(n0 + pr) << 10) + m0 + mq) = xv;
  }
}

// ---------------- K3: per-(r,n) row max and sum-exp over X ----------------
__global__ __launch_bounds__(256) void stats_kernel(
    const _Float16* __restrict__ X, float2* __restrict__ stats) {
  int row = blockIdx.x * 4 + (threadIdx.x >> 6);  // 0..16383 = r*1024+n
  int l = threadIdx.x & 63;
  const f16x8* Sp = (const f16x8*)(X + ((size_t)row << 10) + l * 16);
  f16x8 a = Sp[0], b = Sp[1];
  float v[16];
  float mx = -1e30f;
  #pragma unroll
  for (int i = 0; i < 8; i++) { v[i] = (float)a[i]; v[8 + i] = (float)b[i]; }
  #pragma unroll
  for (int i = 0; i < 16; i++) mx = fmaxf(mx, v[i]);
  #pragma unroll
  for (int off = 32; off >= 1; off >>= 1) mx = fmaxf(mx, __shfl_xor(mx, off, 64));
  float sm = 0.f;
  #pragma unroll
  for (int i = 0; i < 16; i++) sm += __expf(v[i] - mx);
  #pragma unroll
  for (int off = 32; off >= 1; off >>= 1) sm += __shfl_xor(sm, off, 64);
  if (l == 0) stats[row] = make_float2(mx, sm);
}

// ---------------- K4: out[n, r*64+d] = sum_m softmax * V[r,m,d] + f_a ----------------
__global__ __launch_bounds__(256) void pv_kernel(
    const _Float16* __restrict__ S, const float2* __restrict__ stats,
    const float* __restrict__ V, const float* __restrict__ fa,
    float* __restrict__ out) {
  int r = blockIdx.x >> 5;
  int n0 = (blockIdx.x & 31) * 32;
  __shared__ float Pt[64][36];   // [m_local][n_local], padded
  __shared__ float Vt[64][68];   // [m_local][d], padded
  __shared__ float2 st[32];
  int t = threadIdx.x;
  if (t < 32) st[t] = stats[r * NN + n0 + t];

  int d0 = (t & 15) * 4;
  int nl0 = (t >> 4) * 2;
  float acc[2][4] = {};

  for (int m0 = 0; m0 < NN; m0 += 64) {
    __syncthreads();
    {
      int nl = t >> 3;
      int ml = (t & 7) * 8;
      const _Float16* sp = S + ((size_t)r << 20) + ((size_t)(n0 + nl) << 10) + m0 + ml;
      f16x8 sv = *(const f16x8*)sp;
      float mxn = st[nl].x;
      #pragma unroll
      for (int u = 0; u < 8; u++) Pt[ml + u][nl] = __expf((float)sv[u] - mxn);
    }
    {
      int ml = t >> 2;
      int dq = (t & 3) * 16;
      const float* vp = V + ((size_t)r * NN + m0 + ml) * DK + dq;
      #pragma unroll
      for (int u = 0; u < 4; u++) {
        float4 vv = ((const float4*)vp)[u];
        *(float4*)&Vt[ml][dq + u * 4] = vv;
      }
    }
    __syncthreads();
    #pragma unroll 8
    for (int ml = 0; ml < 64; ml++) {
      float a0 = Pt[ml][nl0];
      float a1 = Pt[ml][nl0 + 1];
      float4 vv = *(const float4*)&Vt[ml][d0];
      acc[0][0] += a0 * vv.x; acc[0][1] += a0 * vv.y;
      acc[0][2] += a0 * vv.z; acc[0][3] += a0 * vv.w;
      acc[1][0] += a1 * vv.x; acc[1][1] += a1 * vv.y;
      acc[1][2] += a1 * vv.z; acc[1][3] += a1 * vv.w;
    }
  }

  #pragma unroll
  for (int i = 0; i < 2; i++) {
    int n = n0 + nl0 + i;
    float rs = 1.0f / st[nl0 + i].y;
    int col = r * DK + d0;
    const float4 f = *(const float4*)(fa + (size_t)n * DAPP + col);
    float4 o;
    o.x = acc[i][0] * rs + f.x;
    o.y = acc[i][1] * rs + f.y;
    o.z = acc[i][2] * rs + f.z;
    o.w = acc[i][3] * rs + f.w;
    *(float4*)(out + (size_t)n * DAPP + col) = o;
  }
}

// ---------------- launch ----------------
extern "C" void kernel_launch(void* const* d_in, const int* in_sizes, int n_in,
                              void* d_out, int out_size, void* d_ws, size_t ws_size,
                              hipStream_t stream) {
  const float* fa  = (const float*)d_in[0];
  const float* pe  = (const float*)d_in[1];
  const float* WGw = (const float*)d_in[2];
  const float* WGb = (const float*)d_in[3];
  const float* WKw = (const float*)d_in[4];
  const float* WKb = (const float*)d_in[5];
  const float* WQw = (const float*)d_in[6];
  const float* WQb = (const float*)d_in[7];
  const float* WVw = (const float*)d_in[8];
  const float* WVb = (const float*)d_in[9];
  float* out = (float*)d_out;

  char* ws = (char*)d_ws;
  __bf16* fab = (__bf16*)(ws + OFF_FAB);
  __bf16* wb  = (__bf16*)(ws + OFF_WB);
  __bf16* Kb  = (__bf16*)(ws + OFF_KB);
  __bf16* Qb  = (__bf16*)(ws + OFF_QB);
  float*  V   = (float*)(ws + OFF_V);
  _Float16* X = (_Float16*)(ws + OFF_S);
  float2* st  = (float2*)(ws + OFF_ST);

  // K0: cast (4M elems)
  cast_kernel<<<16384, 256, 0, stream>>>(fa, WKw, WQw, WVw, fab, wb);
  // K1: KQV projection
  kqv_kernel<<<768, 256, 0, stream>>>(fab, wb, WKb, WQb, WVb, Kb, Qb, V);
  // K2: fused MFMA-gate + scores -> X  (4096 wave-jobs, 1024 blocks)
  gate_score_kernel<<<1024, 256, 0, stream>>>(pe, WGw, WGb, Kb, Qb, X);
  // K3: stats (16384 rows, 4/block)
  stats_kernel<<<4096, 256, 0, stream>>>(X, st);
  // K4: PV + residual
  pv_kernel<<<512, 256, 0, stream>>>(X, st, V, fa, out);
}